// Round 1
// baseline (243.698 us; speedup 1.0000x reference)
//
#include <hip/hip_runtime.h>
#include <stdint.h>

#define NBOX 6400
#define GRIDW 80
#define NC 20
#define NBLK 100   // NBOX / 64

__device__ __forceinline__ float sigmoidf(float x) { return 1.0f / (1.0f + expf(-x)); }

__device__ __forceinline__ uint64_t bcast64(uint64_t v, int lane) {
    uint32_t lo = (uint32_t)__shfl((int)(uint32_t)v, lane);
    uint32_t hi = (uint32_t)__shfl((int)(v >> 32), lane);
    return ((uint64_t)hi << 32) | lo;
}

// Kernel 1: per-box decode: conf sigmoid, softmax*conf max/argmax (first-max
// semantics like jnp.argmax), box decode+clip, sort key, class-offset box.
__global__ __launch_bounds__(256) void k_decode(
        const float* __restrict__ pred, float* __restrict__ out,
        uint64_t* __restrict__ key, float4* __restrict__ boff,
        float* __restrict__ score, uint32_t* __restrict__ rownz) {
    int n = blockIdx.x * 256 + threadIdx.x;
    if (n >= NBOX) return;
    const float* p = pred + (size_t)n * 25;
    float conf = sigmoidf(p[0]);
    float c[NC];
    float m = -INFINITY;
    #pragma unroll
    for (int j = 0; j < NC; j++) { c[j] = p[1 + j]; m = fmaxf(m, c[j]); }
    float sum = 0.f;
    #pragma unroll
    for (int j = 0; j < NC; j++) { c[j] = expf(c[j] - m); sum += c[j]; }
    float best = -INFINITY; int bi = 0;
    #pragma unroll
    for (int j = 0; j < NC; j++) {
        float s = (c[j] / sum) * conf;   // replicate softmax*conf then argmax/max
        if (s > best) { best = s; bi = j; }
    }
    // decode box: grid n = gx*80 + gy (meshgrid 'ij')
    float gx = (float)(n / GRIDW);
    float gy = (float)(n % GRIDW);
    float cx = (gx + sigmoidf(p[21])) * 32.0f;
    float cy = (gy + sigmoidf(p[22])) * 32.0f;
    float w = expf(p[23]);
    float h = expf(p[24]);
    float bx1 = fminf(fmaxf((cx - w * 0.5f) / 2560.0f, 0.0f), 1.0f);
    float by1 = fminf(fmaxf((cy - h * 0.5f) / 2560.0f, 0.0f), 1.0f);
    float bx2 = fminf(fmaxf((cx + w * 0.5f) / 2560.0f, 0.0f), 1.0f);
    float by2 = fminf(fmaxf((cy + h * 0.5f) / 2560.0f, 0.0f), 1.0f);

    ((float4*)out)[n] = make_float4(bx1, by1, bx2, by2);   // output 0: boxes
    out[32000 + n] = (float)bi;                            // output 2: class_idx
    score[n] = best;
    // descending score, ascending index tiebreak (stable argsort of -scores)
    key[n] = (((uint64_t)(~__float_as_uint(best))) << 32) | (uint32_t)n;
    float off = 2.0f * (float)bi;                          // class-offset trick
    boff[n] = make_float4(bx1 + off, by1 + off, bx2 + off, by2 + off);
    rownz[n] = 0;                                          // zero-init flags (ws is poisoned)
}

// Kernel 2: rank sort (keys unique -> rank is exact permutation), scatter sorted arrays.
__global__ __launch_bounds__(256) void k_rank(
        const uint64_t* __restrict__ key, const float4* __restrict__ boff,
        const float* __restrict__ score, int* __restrict__ sidx,
        float* __restrict__ sscore, float4* __restrict__ sbox) {
    __shared__ uint64_t klds[NBOX];   // 51.2 KB < 64 KB limit
    int t = threadIdx.x;
    for (int k = t; k < NBOX; k += 256) klds[k] = key[k];
    __syncthreads();
    int n = blockIdx.x * 256 + t;
    uint64_t mykey = klds[n];
    int rank = 0;
    #pragma unroll 16
    for (int j = 0; j < NBOX; j++) rank += (klds[j] < mykey) ? 1 : 0;  // LDS broadcast reads
    sidx[rank] = n;
    sscore[rank] = score[n];
    sbox[rank] = boff[n];
}

// Kernel 3: pairwise suppression mask, 64-bit column blocks, upper triangle only.
__global__ __launch_bounds__(64) void k_mask(const float4* __restrict__ sbox,
        uint64_t* __restrict__ mask, uint32_t* __restrict__ rownz) {
    int bi = blockIdx.y, bj = blockIdx.x;
    if (bj < bi) return;
    int t = threadIdx.x;
    __shared__ float4 cb[64];
    cb[t] = sbox[bj * 64 + t];
    __syncthreads();
    int i = bi * 64 + t;
    float4 rb = sbox[i];
    float areai = (rb.z - rb.x) * (rb.w - rb.y);
    uint64_t bits = 0;
    #pragma unroll 4
    for (int s = 0; s < 64; s++) {
        int j = bj * 64 + s;
        float4 b = cb[s];                        // same addr across lanes -> broadcast
        float xx1 = fmaxf(rb.x, b.x);
        float yy1 = fmaxf(rb.y, b.y);
        float xx2 = fminf(rb.z, b.z);
        float yy2 = fminf(rb.w, b.w);
        float ww = fmaxf(1e-28f, xx2 - xx1);     // EPS clamp exactly as reference
        float hh = fmaxf(1e-28f, yy2 - yy1);
        float inter = ww * hh;
        float areaj = (b.z - b.x) * (b.w - b.y);
        float iou = inter / (areai + areaj - inter);
        if (j > i && iou > 0.5f) bits |= (1ull << s);
    }
    mask[(size_t)i * NBLK + bj] = bits;
    if (bits) atomicOr(&rownz[i], 1u);           // rare: suppressions are sparse
}

// Kernel 4: exact greedy NMS closure, single wave, wave-synchronous (no barriers).
// Lane l owns removed-bitmask words l and l+64. Fast paths skip work when no
// suppression bits exist (the overwhelmingly common case for this data).
__global__ __launch_bounds__(64) void k_scan(
        const uint64_t* __restrict__ mask, const float* __restrict__ sscore,
        const int* __restrict__ sidx, const uint32_t* __restrict__ rownz,
        float* __restrict__ out) {
    int l = threadIdx.x;
    uint64_t r0 = 0, r1 = 0;          // removed words l, l+64
    float* out_score = out + 25600;   // output 1: scores * keep
    float* out_keep  = out + 38400;   // output 3: keep
    for (int c = 0; c < NBLK; c++) {
        uint64_t mine = (c < 64) ? r0 : r1;
        uint64_t rw = bcast64(mine, c & 63);      // removed word for this chunk
        int i = c * 64 + l;
        float s = sscore[i];
        uint64_t vw = __ballot(s >= 0.01f);       // conf-valid bits
        uint64_t m_l = mask[(size_t)i * NBLK + c]; // my row's intra-chunk word
        uint64_t cand = vw & ~rw;
        uint64_t anym = __ballot(m_l != 0);
        uint64_t keep_bits;
        if ((anym & cand) == 0) {
            keep_bits = cand;                     // fast path: no intra suppression possible
        } else {
            keep_bits = 0;
            for (int b = 0; b < 64; b++) {        // exact sequential greedy within chunk
                uint64_t mb = bcast64(m_l, b);
                if (((vw >> b) & 1) && !((rw >> b) & 1)) {
                    keep_bits |= (1ull << b);
                    rw |= mb;
                }
            }
        }
        // cross-chunk propagation: OR mask rows of kept boxes that have any bits
        uint32_t nzf = rownz[i];
        uint64_t nzw = __ballot(nzf != 0);
        uint64_t active = keep_bits & nzw;        // uniform
        if (active != 0) {
            for (int b = 0; b < 64; b++) {
                if ((active >> b) & 1) {
                    const uint64_t* row = mask + (size_t)(c * 64 + b) * NBLK;
                    if (l >= c) r0 |= row[l];
                    if (l < NBLK - 64 && l + 64 >= c) r1 |= row[l + 64];
                }
            }
        }
        // finalize this chunk's outputs (scatter back to original order)
        int orig = sidx[i];
        uint32_t kb = (uint32_t)((keep_bits >> l) & 1);
        out_keep[orig] = (float)kb;
        out_score[orig] = kb ? s : 0.0f;
    }
}

extern "C" void kernel_launch(void* const* d_in, const int* in_sizes, int n_in,
                              void* d_out, int out_size, void* d_ws, size_t ws_size,
                              hipStream_t stream) {
    const float* pred = (const float*)d_in[0];
    float* out = (float*)d_out;
    char* ws = (char*)d_ws;
    // ws layout (bytes): key[6400]u64 @0, boff[6400]f4 @51200, score @153600,
    // sidx @179200, sscore @204800, sbox @230400, mask[6400*100]u64 @332800,
    // rownz[6400]u32 @5452800  (total ~5.48 MB)
    uint64_t* key    = (uint64_t*)(ws + 0);
    float4*   boff   = (float4*)(ws + 51200);
    float*    score  = (float*)(ws + 153600);
    int*      sidx   = (int*)(ws + 179200);
    float*    sscore = (float*)(ws + 204800);
    float4*   sbox   = (float4*)(ws + 230400);
    uint64_t* mask   = (uint64_t*)(ws + 332800);
    uint32_t* rownz  = (uint32_t*)(ws + 5452800);

    k_decode<<<25, 256, 0, stream>>>(pred, out, key, boff, score, rownz);
    k_rank<<<25, 256, 0, stream>>>(key, boff, score, sidx, sscore, sbox);
    k_mask<<<dim3(NBLK, NBLK), 64, 0, stream>>>(sbox, mask, rownz);
    k_scan<<<1, 64, 0, stream>>>(mask, sscore, sidx, rownz, out);
}

// Round 2
// 96.055 us; speedup vs baseline: 2.5371x; 2.5371x over previous
//
#include <hip/hip_runtime.h>
#include <stdint.h>

#define NBOX 6400
#define GRIDW 80
#define NC 20
#define NBLK 100   // NBOX / 64

__device__ __forceinline__ float sigmoidf(float x) { return 1.0f / (1.0f + expf(-x)); }

__device__ __forceinline__ uint64_t bcast64(uint64_t v, int lane) {
    uint32_t lo = (uint32_t)__shfl((int)(uint32_t)v, lane);
    uint32_t hi = (uint32_t)__shfl((int)(v >> 32), lane);
    return ((uint64_t)hi << 32) | lo;
}

// Kernel 1: per-box decode + sort-key build + zero-init of rank/rownzw.
__global__ __launch_bounds__(256) void k_decode(
        const float* __restrict__ pred, float* __restrict__ out,
        uint64_t* __restrict__ key, float4* __restrict__ boff,
        float* __restrict__ score, uint32_t* __restrict__ rank,
        unsigned long long* __restrict__ rownzw) {
    int n = blockIdx.x * 256 + threadIdx.x;
    if (n >= NBOX) return;
    const float* p = pred + (size_t)n * 25;
    float conf = sigmoidf(p[0]);
    float c[NC];
    float m = -INFINITY;
    #pragma unroll
    for (int j = 0; j < NC; j++) { c[j] = p[1 + j]; m = fmaxf(m, c[j]); }
    float sum = 0.f;
    #pragma unroll
    for (int j = 0; j < NC; j++) { c[j] = expf(c[j] - m); sum += c[j]; }
    float best = -INFINITY; int bi = 0;
    #pragma unroll
    for (int j = 0; j < NC; j++) {
        float s = (c[j] / sum) * conf;   // softmax*conf then first-max argmax
        if (s > best) { best = s; bi = j; }
    }
    float gx = (float)(n / GRIDW);       // meshgrid 'ij': n = gx*80 + gy
    float gy = (float)(n % GRIDW);
    float cx = (gx + sigmoidf(p[21])) * 32.0f;
    float cy = (gy + sigmoidf(p[22])) * 32.0f;
    float w = expf(p[23]);
    float h = expf(p[24]);
    float bx1 = fminf(fmaxf((cx - w * 0.5f) / 2560.0f, 0.0f), 1.0f);
    float by1 = fminf(fmaxf((cy - h * 0.5f) / 2560.0f, 0.0f), 1.0f);
    float bx2 = fminf(fmaxf((cx + w * 0.5f) / 2560.0f, 0.0f), 1.0f);
    float by2 = fminf(fmaxf((cy + h * 0.5f) / 2560.0f, 0.0f), 1.0f);

    ((float4*)out)[n] = make_float4(bx1, by1, bx2, by2);   // output 0: boxes
    out[32000 + n] = (float)bi;                            // output 2: class_idx
    score[n] = best;
    key[n] = (((uint64_t)(~__float_as_uint(best))) << 32) | (uint32_t)n;
    float off = 2.0f * (float)bi;                          // class-offset trick
    boff[n] = make_float4(bx1 + off, by1 + off, bx2 + off, by2 + off);
    rank[n] = 0;                                           // ws is poisoned: zero-init
    if (n < NBLK) rownzw[n] = 0ull;
}

// Kernel 2a: partial rank counts. Block (x,y): n-range x, j-slice y (800 keys via LDS).
__global__ __launch_bounds__(256) void k_rank1(
        const uint64_t* __restrict__ key, uint32_t* __restrict__ rank) {
    __shared__ uint64_t klds[800];
    int t = threadIdx.x;
    int jbase = blockIdx.y * 800;
    for (int k = t; k < 800; k += 256) klds[k] = key[jbase + k];
    __syncthreads();
    int n = blockIdx.x * 256 + t;
    uint64_t mykey = key[n];
    uint32_t cnt = 0;
    #pragma unroll 8
    for (int j = 0; j < 800; j++) cnt += (klds[j] < mykey) ? 1u : 0u;
    atomicAdd(&rank[n], cnt);
}

// Kernel 2b: scatter into sorted order (keys unique -> rank is a permutation).
__global__ __launch_bounds__(256) void k_rank2(
        const uint32_t* __restrict__ rank, const float4* __restrict__ boff,
        const float* __restrict__ score, int* __restrict__ sidx,
        float* __restrict__ sscore, float4* __restrict__ sbox) {
    int n = blockIdx.x * 256 + threadIdx.x;
    uint32_t r = rank[n];
    sidx[r] = n;
    sscore[r] = score[n];
    sbox[r] = boff[n];
}

// Kernel 3: pairwise suppression mask, upper triangle only (5050 linearized blocks).
// Diagonal blocks also emit per-chunk validw/diagnz; every block ORs rownzw.
__global__ __launch_bounds__(64) void k_mask(const float4* __restrict__ sbox,
        const float* __restrict__ sscore, uint64_t* __restrict__ mask,
        unsigned long long* __restrict__ rownzw, uint64_t* __restrict__ diagnz,
        uint64_t* __restrict__ validw) {
    int k = blockIdx.x;
    float disc = (NBLK + 0.5f) * (NBLK + 0.5f) - 2.0f * (float)k;
    int bi = (int)((float)NBLK + 0.5f - sqrtf(disc));
    while (bi * NBLK - bi * (bi - 1) / 2 > k) bi--;
    while ((bi + 1) * NBLK - (bi + 1) * bi / 2 <= k) bi++;
    int bj = bi + (k - (bi * NBLK - bi * (bi - 1) / 2));

    int t = threadIdx.x;
    __shared__ float4 cb[64];
    cb[t] = sbox[bj * 64 + t];
    __syncthreads();
    int i = bi * 64 + t;
    float4 rb = sbox[i];
    float areai = (rb.z - rb.x) * (rb.w - rb.y);
    uint64_t bits = 0;
    #pragma unroll 4
    for (int s = 0; s < 64; s++) {
        int j = bj * 64 + s;
        float4 b = cb[s];
        float xx1 = fmaxf(rb.x, b.x);
        float yy1 = fmaxf(rb.y, b.y);
        float xx2 = fminf(rb.z, b.z);
        float yy2 = fminf(rb.w, b.w);
        float ww = fmaxf(1e-28f, xx2 - xx1);     // EPS clamp exactly as reference
        float hh = fmaxf(1e-28f, yy2 - yy1);
        float inter = ww * hh;
        float areaj = (b.z - b.x) * (b.w - b.y);
        float iou = inter / (areai + areaj - inter);
        if (j > i && iou > 0.5f) bits |= (1ull << s);
    }
    mask[(size_t)i * NBLK + bj] = bits;
    uint64_t rn = __ballot(bits != 0);
    if (bi == bj) {
        uint64_t vb = __ballot(sscore[i] >= 0.01f);
        if (t == 0) { diagnz[bi] = rn; validw[bi] = vb; }
    }
    if (t == 0 && rn) atomicOr(&rownzw[bi], (unsigned long long)rn);
}

// Kernel 4: greedy NMS closure, single wave. Fast path: if no valid row anywhere
// has any suppression bits, keep == valid (one ballot). Cold path: exact greedy
// over preloaded per-chunk words via shfl broadcast; global loads only in the
// doubly-rare suppression sub-paths.
__global__ __launch_bounds__(64) void k_scan(
        const uint64_t* __restrict__ mask, const uint64_t* __restrict__ validw,
        const uint64_t* __restrict__ diagnz, const unsigned long long* __restrict__ rownzw,
        uint64_t* __restrict__ keepw) {
    int l = threadIdx.x;
    int l2 = l + 64;
    uint64_t v0 = validw[l],  v1 = (l2 < NBLK) ? validw[l2] : 0ull;
    uint64_t d0 = diagnz[l],  d1 = (l2 < NBLK) ? diagnz[l2] : 0ull;
    uint64_t z0 = rownzw[l],  z1 = (l2 < NBLK) ? rownzw[l2] : 0ull;

    uint64_t conflict = (z0 & v0) | (z1 & v1);
    if (__ballot(conflict != 0ull) == 0ull) {
        keepw[l] = v0;                 // fast path: no valid box suppresses anything
        if (l2 < NBLK) keepw[l2] = v1;
        return;
    }
    // exact sequential greedy closure (cold)
    uint64_t r0 = 0, r1 = 0, k0 = 0, k1 = 0;
    for (int c = 0; c < NBLK; c++) {
        int owner = c & 63;
        bool lo = c < 64;
        uint64_t vw = bcast64(lo ? v0 : v1, owner);
        uint64_t rw = bcast64(lo ? r0 : r1, owner);
        uint64_t dz = bcast64(lo ? d0 : d1, owner);
        uint64_t nz = bcast64(lo ? z0 : z1, owner);
        uint64_t cand = vw & ~rw;
        uint64_t keep;
        if ((dz & cand) == 0ull) {
            keep = cand;
        } else {
            int i = c * 64 + l;
            uint64_t m_l = mask[(size_t)i * NBLK + c];
            keep = 0;
            for (int b = 0; b < 64; b++) {
                uint64_t mb = bcast64(m_l, b);
                if (((vw >> b) & 1ull) && !((rw >> b) & 1ull)) {
                    keep |= (1ull << b);
                    rw |= mb;
                }
            }
        }
        uint64_t active = keep & nz;
        if (active != 0ull) {
            for (int b = 0; b < 64; b++) {
                if ((active >> b) & 1ull) {
                    const uint64_t* row = mask + (size_t)(c * 64 + b) * NBLK;
                    if (l >= c) r0 |= row[l];
                    if (l2 < NBLK && l2 >= c) r1 |= row[l2];
                }
            }
        }
        if (l == owner) { if (lo) k0 = keep; else k1 = keep; }
    }
    keepw[l] = k0;
    if (l2 < NBLK) keepw[l2] = k1;
}

// Kernel 5: parallel finalize — scatter keep/scores back to original order.
__global__ __launch_bounds__(256) void k_final(
        const uint64_t* __restrict__ keepw, const float* __restrict__ sscore,
        const int* __restrict__ sidx, float* __restrict__ out) {
    int i = blockIdx.x * 256 + threadIdx.x;
    int c = i >> 6, b = i & 63;
    uint32_t kb = (uint32_t)((keepw[c] >> b) & 1ull);
    int orig = sidx[i];
    float s = sscore[i];
    out[38400 + orig] = (float)kb;               // output 3: keep
    out[25600 + orig] = kb ? s : 0.0f;           // output 1: scores * keep
}

extern "C" void kernel_launch(void* const* d_in, const int* in_sizes, int n_in,
                              void* d_out, int out_size, void* d_ws, size_t ws_size,
                              hipStream_t stream) {
    const float* pred = (const float*)d_in[0];
    float* out = (float*)d_out;
    char* ws = (char*)d_ws;
    uint64_t* key    = (uint64_t*)(ws + 0);          // 6400 u64
    float4*   boff   = (float4*)(ws + 51200);        // 6400 f4
    float*    score  = (float*)(ws + 153600);        // 6400 f32
    uint32_t* rank   = (uint32_t*)(ws + 179200);     // 6400 u32
    int*      sidx   = (int*)(ws + 204800);          // 6400 i32
    float*    sscore = (float*)(ws + 230400);        // 6400 f32
    float4*   sbox   = (float4*)(ws + 256000);       // 6400 f4
    uint64_t* mask   = (uint64_t*)(ws + 358400);     // 6400*100 u64
    unsigned long long* rownzw = (unsigned long long*)(ws + 5478400); // 100 u64
    uint64_t* diagnz = (uint64_t*)(ws + 5479200);    // 100 u64
    uint64_t* validw = (uint64_t*)(ws + 5480000);    // 100 u64
    uint64_t* keepw  = (uint64_t*)(ws + 5480800);    // 100 u64

    k_decode<<<25, 256, 0, stream>>>(pred, out, key, boff, score, rank, rownzw);
    k_rank1<<<dim3(25, 8), 256, 0, stream>>>(key, rank);
    k_rank2<<<25, 256, 0, stream>>>(rank, boff, score, sidx, sscore, sbox);
    k_mask<<<5050, 64, 0, stream>>>(sbox, sscore, mask, rownzw, diagnz, validw);
    k_scan<<<1, 64, 0, stream>>>(mask, validw, diagnz, rownzw, keepw);
    k_final<<<25, 256, 0, stream>>>(keepw, sscore, sidx, out);
}

// Round 3
// 93.312 us; speedup vs baseline: 2.6117x; 1.0294x over previous
//
#include <hip/hip_runtime.h>
#include <stdint.h>

#define NBOX 6400
#define GRIDW 80
#define NC 20
#define NBLK 100   // NBOX / 64

__device__ __forceinline__ float sigmoidf(float x) { return 1.0f / (1.0f + expf(-x)); }

// Full per-box decode, identical formula everywhere (bit-identical results).
__device__ __forceinline__ void decode_one(const float* __restrict__ p, int n,
        float4* box, float* score, int* cls) {
    float conf = sigmoidf(p[0]);
    float c[NC];
    float m = -INFINITY;
    #pragma unroll
    for (int j = 0; j < NC; j++) { c[j] = p[1 + j]; m = fmaxf(m, c[j]); }
    float sum = 0.f;
    #pragma unroll
    for (int j = 0; j < NC; j++) { c[j] = expf(c[j] - m); sum += c[j]; }
    float best = -INFINITY; int bi = 0;
    #pragma unroll
    for (int j = 0; j < NC; j++) {
        float s = (c[j] / sum) * conf;        // softmax*conf, first-max argmax
        if (s > best) { best = s; bi = j; }
    }
    float gx = (float)(n / GRIDW);            // meshgrid 'ij': n = gx*80 + gy
    float gy = (float)(n % GRIDW);
    float cx = (gx + sigmoidf(p[21])) * 32.0f;
    float cy = (gy + sigmoidf(p[22])) * 32.0f;
    float w = expf(p[23]);
    float h = expf(p[24]);
    box->x = fminf(fmaxf((cx - w * 0.5f) / 2560.0f, 0.0f), 1.0f);
    box->y = fminf(fmaxf((cy - h * 0.5f) / 2560.0f, 0.0f), 1.0f);
    box->z = fminf(fmaxf((cx + w * 0.5f) / 2560.0f, 0.0f), 1.0f);
    box->w = fminf(fmaxf((cy + h * 0.5f) / 2560.0f, 0.0f), 1.0f);
    *score = best;
    *cls = bi;
}

// One dispatch: blocks 0..99 decode+write outputs (keep==valid provisional,
// exact when no suppressing pair exists); blocks 100.. test all upper-triangle
// tile pairs for any both-valid IoU>0.5 pair on class-offset boxes -> flag=1.
__global__ __launch_bounds__(64) void k_main(const float* __restrict__ pred,
        float* __restrict__ out, float4* __restrict__ boff,
        float* __restrict__ score_ws, uint32_t* __restrict__ flag) {
    int bid = blockIdx.x;
    int t = threadIdx.x;
    if (bid < NBLK) {                         // ---- decode path ----
        int n = bid * 64 + t;
        float4 bx; float s; int cls;
        decode_one(pred + (size_t)n * 25, n, &bx, &s, &cls);
        ((float4*)out)[n] = bx;               // output 0: boxes
        out[32000 + n] = (float)cls;          // output 2: class_idx
        bool valid = s >= 0.01f;
        out[25600 + n] = valid ? s : 0.0f;    // output 1: scores*keep (fast path)
        out[38400 + n] = valid ? 1.0f : 0.0f; // output 3: keep (fast path)
        score_ws[n] = s;
        float off = 2.0f * (float)cls;        // class-offset trick
        boff[n] = make_float4(bx.x + off, bx.y + off, bx.z + off, bx.w + off);
        return;
    }
    // ---- pair-test path: linearized upper triangle (bi<=bj) ----
    int k = bid - NBLK;
    float disc = (NBLK + 0.5f) * (NBLK + 0.5f) - 2.0f * (float)k;
    int bi = (int)((float)NBLK + 0.5f - sqrtf(disc));
    while (bi * NBLK - bi * (bi - 1) / 2 > k) bi--;
    while ((bi + 1) * NBLK - (bi + 1) * bi / 2 <= k) bi++;
    int bj = bi + (k - (bi * NBLK - bi * (bi - 1) / 2));

    __shared__ float4 cb[64];
    int jcol = bj * 64 + t;
    float4 cbox; float cs; int ccls;
    decode_one(pred + (size_t)jcol * 25, jcol, &cbox, &cs, &ccls);
    float coff = 2.0f * (float)ccls;
    cb[t] = make_float4(cbox.x + coff, cbox.y + coff, cbox.z + coff, cbox.w + coff);
    __syncthreads();
    uint64_t colvalid = __ballot(cs >= 0.01f);

    int i = bi * 64 + t;
    float4 rbox; float rs; int rcls;
    decode_one(pred + (size_t)i * 25, i, &rbox, &rs, &rcls);
    float roff = 2.0f * (float)rcls;
    float rx1 = rbox.x + roff, ry1 = rbox.y + roff;
    float rx2 = rbox.z + roff, ry2 = rbox.w + roff;
    float areai = (rx2 - rx1) * (ry2 - ry1);

    bool hit = false;
    if ((rs >= 0.01f) && colvalid != 0ull) {
        for (int s = 0; s < 64; s++) {
            if (!((colvalid >> s) & 1ull)) continue;
            int j = bj * 64 + s;
            if (bi == bj && j <= i) continue;        // unordered pairs once
            float4 b = cb[s];
            float xx1 = fmaxf(rx1, b.x);
            float yy1 = fmaxf(ry1, b.y);
            float xx2 = fminf(rx2, b.z);
            float yy2 = fminf(ry2, b.w);
            float ww = fmaxf(1e-28f, xx2 - xx1);     // EPS exactly as reference
            float hh = fmaxf(1e-28f, yy2 - yy1);
            float inter = ww * hh;
            float areaj = (b.z - b.x) * (b.w - b.y);
            float iou = inter / (areai + areaj - inter);
            if (iou > 0.5f) { hit = true; break; }
        }
    }
    if (__ballot(hit) != 0ull) {
        if (t == 0) flag[0] = 1u;     // benign race: all writers store 1
    }
}

// Rare exact path: flag==1 -> full NMS (rank sort + sequential greedy) and
// rewrite outputs. flag!=1 (0xAAAAAAAA poison or untouched) -> exit in ~1us.
__global__ __launch_bounds__(1024) void k_fixup(
        const uint32_t* __restrict__ flag, const float* __restrict__ score,
        const float4* __restrict__ boff, int* __restrict__ sidx,
        float* __restrict__ sscore, float4* __restrict__ sbox,
        float* __restrict__ out) {
    if (flag[0] != 1u) return;
    __shared__ uint64_t klds[NBOX];       // 51.2 KB
    __shared__ uint32_t keepb[NBOX / 32]; // 800 B
    int t = threadIdx.x;
    for (int n = t; n < NBOX; n += 1024) {
        // stable argsort of -scores: (desc score, asc index)
        klds[n] = (((uint64_t)(~__float_as_uint(score[n]))) << 32) | (uint32_t)n;
    }
    __syncthreads();
    for (int n = t; n < NBOX; n += 1024) {
        uint64_t mk = klds[n];
        int r = 0;
        for (int j = 0; j < NBOX; j++) r += (klds[j] < mk) ? 1 : 0;
        sidx[r] = n;
        sscore[r] = score[n];
        sbox[r] = boff[n];
    }
    __syncthreads();
    for (int w2 = t; w2 < NBOX / 32; w2 += 1024) {
        uint32_t v = 0;
        for (int b = 0; b < 32; b++) v |= (sscore[w2 * 32 + b] >= 0.01f) ? (1u << b) : 0u;
        keepb[w2] = v;
    }
    __syncthreads();
    for (int i = 0; i < NBOX; i++) {
        bool kept = (keepb[i >> 5] >> (i & 31)) & 1u;   // uniform (LDS broadcast)
        if (kept) {
            float4 a = sbox[i];
            float areai = (a.z - a.x) * (a.w - a.y);
            for (int j = i + 1 + t; j < NBOX; j += 1024) {
                if ((keepb[j >> 5] >> (j & 31)) & 1u) {
                    float4 b = sbox[j];
                    float xx1 = fmaxf(a.x, b.x);
                    float yy1 = fmaxf(a.y, b.y);
                    float xx2 = fminf(a.z, b.z);
                    float yy2 = fminf(a.w, b.w);
                    float ww = fmaxf(1e-28f, xx2 - xx1);
                    float hh = fmaxf(1e-28f, yy2 - yy1);
                    float inter = ww * hh;
                    float areaj = (b.z - b.x) * (b.w - b.y);
                    float iou = inter / (areai + areaj - inter);
                    if (iou > 0.5f) atomicAnd(&keepb[j >> 5], ~(1u << (j & 31)));
                }
            }
        }
        __syncthreads();
    }
    for (int r = t; r < NBOX; r += 1024) {
        int orig = sidx[r];
        uint32_t kb = (keepb[r >> 5] >> (r & 31)) & 1u;
        out[38400 + orig] = (float)kb;
        out[25600 + orig] = kb ? sscore[r] : 0.0f;
    }
}

extern "C" void kernel_launch(void* const* d_in, const int* in_sizes, int n_in,
                              void* d_out, int out_size, void* d_ws, size_t ws_size,
                              hipStream_t stream) {
    const float* pred = (const float*)d_in[0];
    float* out = (float*)d_out;
    char* ws = (char*)d_ws;
    float4*   boff   = (float4*)(ws + 0);        // 6400 f4   (102400 B)
    float*    score  = (float*)(ws + 102400);    // 6400 f32
    int*      sidx   = (int*)(ws + 128000);      // 6400 i32  (slow path only)
    float*    sscore = (float*)(ws + 153600);    // 6400 f32  (slow path only)
    float4*   sbox   = (float4*)(ws + 179200);   // 6400 f4   (slow path only)
    uint32_t* flag   = (uint32_t*)(ws + 281600); // 1 u32 (poison != 1 => clean)

    k_main<<<NBLK + 5050, 64, 0, stream>>>(pred, out, boff, score, flag);
    k_fixup<<<1, 1024, 0, stream>>>(flag, score, boff, sidx, sscore, sbox, out);
}

// Round 4
// 73.075 us; speedup vs baseline: 3.3349x; 1.2769x over previous
//
#include <hip/hip_runtime.h>
#include <stdint.h>

#define NBOX 6400
#define GRIDW 80
#define NC 20
#define NBLK 100   // NBOX / 64

__device__ __forceinline__ float sigmoidf(float x) { return 1.0f / (1.0f + expf(-x)); }

// Full per-box decode, exact reference formulas (outputs must be bit-faithful).
__device__ __forceinline__ void decode_one(const float* __restrict__ p, int n,
        float4* box, float* score, int* cls) {
    float conf = sigmoidf(p[0]);
    float c[NC];
    float m = -INFINITY;
    #pragma unroll
    for (int j = 0; j < NC; j++) { c[j] = p[1 + j]; m = fmaxf(m, c[j]); }
    float sum = 0.f;
    #pragma unroll
    for (int j = 0; j < NC; j++) { c[j] = expf(c[j] - m); sum += c[j]; }
    float best = -INFINITY; int bi = 0;
    #pragma unroll
    for (int j = 0; j < NC; j++) {
        float s = (c[j] / sum) * conf;        // softmax*conf, first-max argmax
        if (s > best) { best = s; bi = j; }
    }
    float gx = (float)(n / GRIDW);            // meshgrid 'ij': n = gx*80 + gy
    float gy = (float)(n % GRIDW);
    float cx = (gx + sigmoidf(p[21])) * 32.0f;
    float cy = (gy + sigmoidf(p[22])) * 32.0f;
    float w = expf(p[23]);
    float h = expf(p[24]);
    box->x = fminf(fmaxf((cx - w * 0.5f) / 2560.0f, 0.0f), 1.0f);
    box->y = fminf(fmaxf((cy - h * 0.5f) / 2560.0f, 0.0f), 1.0f);
    box->z = fminf(fmaxf((cx + w * 0.5f) / 2560.0f, 0.0f), 1.0f);
    box->w = fminf(fmaxf((cy + h * 0.5f) / 2560.0f, 0.0f), 1.0f);
    *score = best;
    *cls = bi;
}

// Kernel 1 (100 blocks x 64): decode + write all outputs (keep==valid, exact
// when no suppressing pair exists) + per-block screen data: un-offset bbox
// over VALID lanes (shfl_xor reduce) and valid ballot.
__global__ __launch_bounds__(64) void k_decode(const float* __restrict__ pred,
        float* __restrict__ out, float4* __restrict__ boff,
        float* __restrict__ score_ws, float4* __restrict__ blkbb,
        uint64_t* __restrict__ validw) {
    int t = threadIdx.x;
    int n = blockIdx.x * 64 + t;
    float4 bx; float s; int cls;
    decode_one(pred + (size_t)n * 25, n, &bx, &s, &cls);
    ((float4*)out)[n] = bx;               // output 0: boxes
    out[32000 + n] = (float)cls;          // output 2: class_idx
    bool valid = s >= 0.01f;
    out[25600 + n] = valid ? s : 0.0f;    // output 1: scores*keep (fast path)
    out[38400 + n] = valid ? 1.0f : 0.0f; // output 3: keep (fast path)
    score_ws[n] = s;
    float off = 2.0f * (float)cls;        // class-offset trick (matches ref order)
    boff[n] = make_float4(bx.x + off, bx.y + off, bx.z + off, bx.w + off);

    // block bounding box over valid boxes (un-offset geometry)
    float x1 = valid ? bx.x :  INFINITY;
    float y1 = valid ? bx.y :  INFINITY;
    float x2 = valid ? bx.z : -INFINITY;
    float y2 = valid ? bx.w : -INFINITY;
    #pragma unroll
    for (int d = 1; d < 64; d <<= 1) {
        x1 = fminf(x1, __shfl_xor(x1, d));
        y1 = fminf(y1, __shfl_xor(y1, d));
        x2 = fmaxf(x2, __shfl_xor(x2, d));
        y2 = fmaxf(y2, __shfl_xor(y2, d));
    }
    uint64_t vb = __ballot(valid);
    if (t == 0) {
        blkbb[blockIdx.x] = make_float4(x1, y1, x2, y2);
        validw[blockIdx.x] = vb;
    }
}

// Kernel 2 (5050 blocks x 64): upper-triangle block pairs. Cheap bbox screen
// first (most pairs exit immediately); survivors run a div-free conservative
// IoU>0.5 test on the precomputed offset boxes. Any possible hit -> flag=1.
__global__ __launch_bounds__(64) void k_pairs(const float4* __restrict__ boff,
        const float4* __restrict__ blkbb, const uint64_t* __restrict__ validw,
        uint32_t* __restrict__ flag) {
    int k = blockIdx.x;
    float disc = (NBLK + 0.5f) * (NBLK + 0.5f) - 2.0f * (float)k;
    int bi = (int)((float)NBLK + 0.5f - sqrtf(disc));
    while (bi * NBLK - bi * (bi - 1) / 2 > k) bi--;
    while ((bi + 1) * NBLK - (bi + 1) * bi / 2 <= k) bi++;
    int bj = bi + (k - (bi * NBLK - bi * (bi - 1) / 2));

    float4 ra = blkbb[bi];
    float4 ca = blkbb[bj];
    const float M = 1e-5f;   // conservative margin (bbox coords in [0,1])
    bool ov = (fminf(ra.z, ca.z) + M >= fmaxf(ra.x, ca.x)) &&
              (fminf(ra.w, ca.w) + M >= fmaxf(ra.y, ca.y));
    if (!ov) return;         // disjoint blocks: no pair can have IoU>0.5

    int t = threadIdx.x;
    __shared__ float4 cb[64];
    cb[t] = boff[bj * 64 + t];
    __syncthreads();
    uint64_t colvalid = validw[bj];
    uint64_t rowvalid = validw[bi];
    int i = bi * 64 + t;
    float4 rb = boff[i];
    float areai = (rb.z - rb.x) * (rb.w - rb.y);
    bool hit = false;
    if ((rowvalid >> t) & 1ull) {
        for (int s2 = 0; s2 < 64; s2++) {
            if (!((colvalid >> s2) & 1ull)) continue;
            int j = bj * 64 + s2;
            if (bi == bj && j <= i) continue;        // unordered pairs once
            float4 b = cb[s2];
            float xx1 = fmaxf(rb.x, b.x);
            float yy1 = fmaxf(rb.y, b.y);
            float xx2 = fminf(rb.z, b.z);
            float yy2 = fminf(rb.w, b.w);
            float ww = fmaxf(1e-28f, xx2 - xx1);     // EPS exactly as reference
            float hh = fmaxf(1e-28f, yy2 - yy1);
            float inter = ww * hh;
            float areaj = (b.z - b.x) * (b.w - b.y);
            // div-free conservative: iou>0.5 <=> 3*inter > areai+areaj (denom>0);
            // margin covers f32 rounding; also catches denom<=0 inf corner.
            if (3.0f * inter >= 0.9995f * (areai + areaj)) { hit = true; break; }
        }
    }
    if (__ballot(hit) != 0ull) {
        if (t == 0) flag[0] = 1u;     // benign race: all writers store 1
    }
}

// Rare exact path: flag==1 -> full reference NMS (rank sort + sequential greedy)
// and rewrite outputs. flag!=1 (0xAAAAAAAA poison) -> exit immediately.
__global__ __launch_bounds__(1024) void k_fixup(
        const uint32_t* __restrict__ flag, const float* __restrict__ score,
        const float4* __restrict__ boff, int* __restrict__ sidx,
        float* __restrict__ sscore, float4* __restrict__ sbox,
        float* __restrict__ out) {
    if (flag[0] != 1u) return;
    __shared__ uint64_t klds[NBOX];       // 51.2 KB
    __shared__ uint32_t keepb[NBOX / 32]; // 800 B
    int t = threadIdx.x;
    for (int n = t; n < NBOX; n += 1024) {
        // stable argsort of -scores: (desc score, asc index)
        klds[n] = (((uint64_t)(~__float_as_uint(score[n]))) << 32) | (uint32_t)n;
    }
    __syncthreads();
    for (int n = t; n < NBOX; n += 1024) {
        uint64_t mk = klds[n];
        int r = 0;
        for (int j = 0; j < NBOX; j++) r += (klds[j] < mk) ? 1 : 0;
        sidx[r] = n;
        sscore[r] = score[n];
        sbox[r] = boff[n];
    }
    __syncthreads();
    for (int w2 = t; w2 < NBOX / 32; w2 += 1024) {
        uint32_t v = 0;
        for (int b = 0; b < 32; b++) v |= (sscore[w2 * 32 + b] >= 0.01f) ? (1u << b) : 0u;
        keepb[w2] = v;
    }
    __syncthreads();
    for (int i = 0; i < NBOX; i++) {
        bool kept = (keepb[i >> 5] >> (i & 31)) & 1u;   // uniform (LDS broadcast)
        if (kept) {
            float4 a = sbox[i];
            float areai = (a.z - a.x) * (a.w - a.y);
            for (int j = i + 1 + t; j < NBOX; j += 1024) {
                if ((keepb[j >> 5] >> (j & 31)) & 1u) {
                    float4 b = sbox[j];
                    float xx1 = fmaxf(a.x, b.x);
                    float yy1 = fmaxf(a.y, b.y);
                    float xx2 = fminf(a.z, b.z);
                    float yy2 = fminf(a.w, b.w);
                    float ww = fmaxf(1e-28f, xx2 - xx1);
                    float hh = fmaxf(1e-28f, yy2 - yy1);
                    float inter = ww * hh;
                    float areaj = (b.z - b.x) * (b.w - b.y);
                    float iou = inter / (areai + areaj - inter);   // exact ref formula
                    if (iou > 0.5f) atomicAnd(&keepb[j >> 5], ~(1u << (j & 31)));
                }
            }
        }
        __syncthreads();
    }
    for (int r = t; r < NBOX; r += 1024) {
        int orig = sidx[r];
        uint32_t kb = (keepb[r >> 5] >> (r & 31)) & 1u;
        out[38400 + orig] = (float)kb;
        out[25600 + orig] = kb ? sscore[r] : 0.0f;
    }
}

extern "C" void kernel_launch(void* const* d_in, const int* in_sizes, int n_in,
                              void* d_out, int out_size, void* d_ws, size_t ws_size,
                              hipStream_t stream) {
    const float* pred = (const float*)d_in[0];
    float* out = (float*)d_out;
    char* ws = (char*)d_ws;
    float4*   boff   = (float4*)(ws + 0);        // 6400 f4  (102400 B)
    float*    score  = (float*)(ws + 102400);    // 6400 f32
    float4*   blkbb  = (float4*)(ws + 128000);   // 100 f4 block bboxes
    uint64_t* validw = (uint64_t*)(ws + 129600); // 100 u64 valid ballots
    uint32_t* flag   = (uint32_t*)(ws + 130432); // 1 u32 (poison != 1 => clean)
    int*      sidx   = (int*)(ws + 131072);      // slow path only
    float*    sscore = (float*)(ws + 156672);    // slow path only
    float4*   sbox   = (float4*)(ws + 182272);   // slow path only

    k_decode<<<NBLK, 64, 0, stream>>>(pred, out, boff, score, blkbb, validw);
    k_pairs<<<5050, 64, 0, stream>>>(boff, blkbb, validw, flag);
    k_fixup<<<1, 1024, 0, stream>>>(flag, score, boff, sidx, sscore, sbox, out);
}